// Round 5
// baseline (462.101 us; speedup 1.0000x reference)
//
#include <hip/hip_runtime.h>

// BoxCrossCategoryLoss: streaming row-wise loss over 6 x (N,2) f32 arrays.
// int index inputs are unused by the reference (recipes are constants).
//
// R5: packed-fp32 compute. R4 counters showed ~440 VALU instrs per row-pair
// (VALUBusy 33% x 137us = 45us busy) -- 2x my hand count, from address
// chains, cur=nxt copies, masks. Now: the two rows of each float4 segment
// run identical math -> compute them as <2 x float> ext-vectors so
// adds/muls/fmas lower to v_pk_*_f32 (half the issue slots); trans + max
// stay scalar. Fast-path kernel has NO bounds checks (16M % (2048*256*4)
// == 0); masked generic kernel is the fallback. unroll 2 kills the
// double-buffer copies.

#define LOG2E 1.4426950408889634f
#define LN2   0.6931471805599453f

typedef float v2f __attribute__((ext_vector_type(2)));

__device__ __forceinline__ float fexp2s(float x) { return __builtin_amdgcn_exp2f(x); }
__device__ __forceinline__ float flog2s(float x) { return __builtin_amdgcn_logf(x); }

__device__ __forceinline__ v2f vexp2(v2f x) { v2f r; r.x = fexp2s(x.x); r.y = fexp2s(x.y); return r; }
__device__ __forceinline__ v2f vlog2(v2f x) { v2f r; r.x = flog2s(x.x); r.y = flog2s(x.y); return r; }
__device__ __forceinline__ v2f vrelu(v2f x) { v2f r; r.x = fmaxf(x.x, 0.0f); r.y = fmaxf(x.y, 0.0f); return r; }

struct Seg { float4 ab, ba, bc, cb, ac, ca; };

// Loss for the 2 rows of one segment, in LOG2 UNITS, packed 2-wide.
// Lane .x = row0 (float4 .x/.y), lane .y = row1 (float4 .z/.w).
__device__ __forceinline__ v2f seg_loss(const Seg& s)
{
    // repack: col0 = (x,z), col1 = (y,w)
    v2f a0 = {s.ab.x, s.ab.z}, a1 = {s.ab.y, s.ab.w};
    v2f b0 = {s.ba.x, s.ba.z}, b1 = {s.ba.y, s.ba.w};
    v2f c0 = {s.bc.x, s.bc.z}, c1 = {s.bc.y, s.bc.w};
    v2f d0 = {s.cb.x, s.cb.z}, d1 = {s.cb.y, s.cb.w};
    v2f e0 = {s.ac.x, s.ac.z}, e1 = {s.ac.y, s.ac.w};
    v2f f0 = {s.ca.x, s.ca.z}, f1 = {s.ca.y, s.ca.w};

    // scaled inputs (log2 units) — also the exp2 arguments (v_pk_mul_f32)
    v2f a0s = a0 * LOG2E, a1s = a1 * LOG2E;
    v2f b0s = b0 * LOG2E, b1s = b1 * LOG2E;
    v2f c0s = c0 * LOG2E, c1s = c1 * LOG2E;
    v2f d0s = d0 * LOG2E, d1s = d1 * LOG2E;
    v2f e0s = e0 * LOG2E, e1s = e1 * LOG2E;
    v2f f0s = f0 * LOG2E, f1s = f1 * LOG2E;

    // u = exp(x) via hardware exp2 (scalar trans); w = 1 - u (packed)
    v2f ua0 = vexp2(a0s), ub0 = vexp2(b0s), uc0 = vexp2(c0s), ud0 = vexp2(d0s);
    v2f ue0 = vexp2(e0s), uf0 = vexp2(f0s);
    v2f ua1 = vexp2(a1s), ub1 = vexp2(b1s), uc1 = vexp2(c1s), ud1 = vexp2(d1s);
    v2f ue1 = vexp2(e1s), uf1 = vexp2(f1s);

    v2f wa0 = 1.0f - ua0, wb0 = 1.0f - ub0, wc0 = 1.0f - uc0, wd0 = 1.0f - ud0;
    v2f we0 = 1.0f - ue0, wf0 = 1.0f - uf0;
    v2f wa1 = 1.0f - ua1, wb1 = 1.0f - ub1, wc1 = 1.0f - uc1, wd1 = 1.0f - ud1;
    v2f we1 = 1.0f - ue1, wf1 = 1.0f - uf1;

    // l = log2(1 - exp(x)) (10 needed individually; le0/lf0 via product form)
    v2f la0 = vlog2(wa0), lb0 = vlog2(wb0), lc0 = vlog2(wc0), ld0 = vlog2(wd0);
    v2f la1 = vlog2(wa1), lb1 = vlog2(wb1), lc1 = vlog2(wc1), ld1 = vlog2(wd1);
    v2f le1 = vlog2(we1), lf1 = vlog2(wf1);

    // LACk = log1mexp(pAC[k][:,0]) in log2 units (pk_fma + scalar log)
    v2f LAC0 = vlog2(1.0f - ue0 * wf0);
    v2f LAC1 = vlog2(1.0f - we0 * uf0);
    v2f LAC2 = vlog2(1.0f - ue0 * uf0);

    // p[k] = [v1+l2, l1+v2, v1+v2, l1+l2]  (log2 units, pk_add)
    v2f AB00 = a0s + lb0, AB10 = la0 + b0s, AB20 = a0s + b0s;
    v2f AB01 = a1s + lb1, AB11 = la1 + b1s, AB21 = a1s + b1s, AB31 = la1 + lb1;
    v2f BC00 = c0s + ld0, BC10 = lc0 + d0s, BC20 = c0s + d0s;
    v2f BC01 = c1s + ld1, BC11 = lc1 + d1s, BC21 = c1s + d1s, BC31 = lc1 + ld1;
    v2f AC01 = e1s + lf1, AC11 = le1 + f1s, AC21 = e1s + f1s, AC31 = le1 + lf1;

    // 14 unique AB+BC sums shared across the 36 terms.
    v2f s1  = AB00 + BC01, s2  = AB00 + BC21, s3  = AB10 + BC11, s4  = AB10 + BC21;
    v2f s5  = AB20 + BC01, s6  = AB20 + BC11, s7  = AB20 + BC21, s8  = AB20 + BC31;
    v2f s9  = AB01 + BC00, s10 = AB01 + BC20, s11 = AB11 + BC10, s12 = AB11 + BC20;
    v2f s13 = AB21 + BC20, s14 = AB31 + BC20;

    // Two independent accumulator chains for add ILP.
    v2f p = {0.0f, 0.0f}, q = {0.0f, 0.0f};
    // LOSS_RECIPE (14 terms)
    p += vrelu(s1 - AC01) + vrelu(s2 - AC01) + vrelu(s3 - AC11) + vrelu(s4 - AC11);
    q += vrelu(s5 - AC01) + vrelu(s6 - AC11) + vrelu(s7 - AC21) + vrelu(s8 - AC31);
    p += vrelu(s9 - AC01) + vrelu(s10 - AC01) + vrelu(s11 - AC11) + vrelu(s12 - AC11);
    q += vrelu(s13 - AC21) + vrelu(s14 - AC31);
    // NEG_LOSS_RECIPE (22 terms)
    p += vrelu(s1 - LAC1) + vrelu(s1 - LAC2) + vrelu(s2 - LAC1) + vrelu(s2 - LAC2);
    q += vrelu(s3 - LAC0) + vrelu(s3 - LAC2) + vrelu(s4 - LAC0) + vrelu(s4 - LAC2);
    p += vrelu(s5 - LAC1) + vrelu(s5 - LAC2) + vrelu(s6 - LAC0) + vrelu(s6 - LAC2);
    q += vrelu(s9 - LAC1) + vrelu(s9 - LAC2) + vrelu(s10 - LAC1) + vrelu(s10 - LAC2);
    p += vrelu(s11 - LAC0) + vrelu(s11 - LAC2) + vrelu(s12 - LAC0) + vrelu(s12 - LAC2);
    q += vrelu(s8 - LAC2) + vrelu(s14 - LAC2);
    return p + q;  // log2 units, per-row in .x/.y
}

__device__ __forceinline__ void load_seg(Seg& s,
    const float* __restrict__ AB, const float* __restrict__ BA,
    const float* __restrict__ BC, const float* __restrict__ CB,
    const float* __restrict__ AC, const float* __restrict__ CA, long off)
{
    s.ab = *(const float4*)(AB + off);
    s.ba = *(const float4*)(BA + off);
    s.bc = *(const float4*)(BC + off);
    s.cb = *(const float4*)(CB + off);
    s.ac = *(const float4*)(AC + off);
    s.ca = *(const float4*)(CA + off);
}

template <bool CHECKED>
__global__ __launch_bounds__(256, 4) void box_loss_kernel(
    const float* __restrict__ AB, const float* __restrict__ BA,
    const float* __restrict__ BC, const float* __restrict__ CB,
    const float* __restrict__ AC, const float* __restrict__ CA,
    float* __restrict__ out, int nIter, long stride, long nElems)
{
    long off = ((long)blockIdx.x * blockDim.x + threadIdx.x) * 4;
    v2f acc = {0.0f, 0.0f};
    Seg cur, nxt;
    float mcur = 1.0f, mnxt = 1.0f;

    long a = off;
    if (CHECKED) {
        bool v = (off + 4) <= nElems;
        a = v ? off : 0;
        mcur = v ? 1.0f : 0.0f;
    }
    load_seg(cur, AB, BA, BC, CB, AC, CA, a);
    off += stride;

    #pragma unroll 2
    for (int it = 1; it < nIter; ++it) {
        long b = off;
        if (CHECKED) {
            bool v = (off + 4) <= nElems;
            b = v ? off : 0;
            mnxt = v ? 1.0f : 0.0f;
        }
        // Prefetch next segment, pinned above current segment's compute.
        load_seg(nxt, AB, BA, BC, CB, AC, CA, b);
        __builtin_amdgcn_sched_barrier(0);
        if (CHECKED) acc += seg_loss(cur) * mcur;
        else         acc += seg_loss(cur);
        cur = nxt;
        mcur = mnxt;
        off += stride;
    }
    if (CHECKED) acc += seg_loss(cur) * mcur;
    else         acc += seg_loss(cur);

    float r = (acc.x + acc.y) * LN2;  // back to natural-log units

    // wave64 butterfly reduce
    #pragma unroll
    for (int o = 32; o > 0; o >>= 1)
        r += __shfl_down(r, o, 64);

    __shared__ float wsum[4];
    const int lane = threadIdx.x & 63;
    const int wid  = threadIdx.x >> 6;
    if (lane == 0) wsum[wid] = r;
    __syncthreads();
    if (threadIdx.x == 0)
        atomicAdd(out, wsum[0] + wsum[1] + wsum[2] + wsum[3]);
}

extern "C" void kernel_launch(void* const* d_in, const int* in_sizes, int n_in,
                              void* d_out, int out_size, void* d_ws, size_t ws_size,
                              hipStream_t stream) {
    const float* AB = (const float*)d_in[0];  // vol_AB
    const float* BA = (const float*)d_in[1];  // vol_BA
    const float* BC = (const float*)d_in[2];  // vol_BC
    const float* CB = (const float*)d_in[3];  // vol_CB
    const float* AC = (const float*)d_in[4];  // vol_AC
    const float* CA = (const float*)d_in[5];  // vol_CA
    // d_in[6..8] (xy/yz/xz rel ids) are unused by the reference.

    const long nElems = in_sizes[0];  // N*2 = 16,777,216 = 2^24
    const int block = 256;
    const int grid = 2048;
    const long stride = (long)grid * block * 4;  // 2^21 — divides 2^24

    // d_out is poisoned with 0xAA before every timed launch — zero it.
    hipMemsetAsync(d_out, 0, (size_t)out_size * sizeof(float), stream);

    if (nElems % stride == 0 && nElems >= stride) {
        const int nIter = (int)(nElems / stride);  // 8
        box_loss_kernel<false><<<grid, block, 0, stream>>>(
            AB, BA, BC, CB, AC, CA, (float*)d_out, nIter, stride, nElems);
    } else {
        const int nIter = (int)((nElems + stride - 1) / stride);
        box_loss_kernel<true><<<grid, block, 0, stream>>>(
            AB, BA, BC, CB, AC, CA, (float*)d_out, nIter, stride, nElems);
    }
}